// Round 9
// baseline (209.227 us; speedup 1.0000x reference)
//
#include <hip/hip_runtime.h>
#include <hip/hip_bf16.h>

#define C_DIM 100000
#define NROW 512
#define DDIM 512
#define BN 64
#define NPANEL 1563            // ceil(C_DIM/64)

typedef __attribute__((ext_vector_type(4))) float f32x4;
typedef __attribute__((ext_vector_type(8))) short bf16x8;
typedef __attribute__((ext_vector_type(4))) unsigned short u16x4;
typedef __attribute__((ext_vector_type(4))) float f32acc;

// ------- kernel 1: norm2[d] = sum_c W[d][c]^2  AND  Wb = bf16(W) (same layout) --
// One streaming pass: sequential 1KB/wave reads, sequential 512B/wave writes.
__global__ __launch_bounds__(256) void cf_knorm2(const float* __restrict__ W,
                                                 float* __restrict__ norm2,
                                                 __hip_bfloat16* __restrict__ Wb) {
    const int d = blockIdx.x;
    const float* row = W + (size_t)d * C_DIM;
    __hip_bfloat16* wrow = Wb + (size_t)d * C_DIM;
    float s = 0.f;
    for (int c4 = threadIdx.x; c4 < C_DIM / 4; c4 += 256) {
        f32x4 v = *(const f32x4*)(row + c4 * 4);
        s += v.x * v.x + v.y * v.y + v.z * v.z + v.w * v.w;
        union { __hip_bfloat16 h[4]; u16x4 u; } p;
        #pragma unroll
        for (int e = 0; e < 4; ++e) p.h[e] = __float2bfloat16(v[e]);
        *(u16x4*)(wrow + c4 * 4) = p.u;
    }
    #pragma unroll
    for (int off = 32; off; off >>= 1) s += __shfl_down(s, off, 64);
    __shared__ float wsum[4];
    if ((threadIdx.x & 63) == 0) wsum[threadIdx.x >> 6] = s;
    __syncthreads();
    if (threadIdx.x == 0) norm2[d] = wsum[0] + wsum[1] + wsum[2] + wsum[3];
}

// ---------------- fallback kernel 1b: norm2 only --------------------------------
__global__ __launch_bounds__(256) void cf_knorm(const float* __restrict__ W,
                                                float* __restrict__ norm2) {
    const int d = blockIdx.x;
    const float* row = W + (size_t)d * C_DIM;
    float s = 0.f;
    for (int c4 = threadIdx.x; c4 < C_DIM / 4; c4 += 256) {
        f32x4 v = *(const f32x4*)(row + c4 * 4);
        s += v.x * v.x + v.y * v.y + v.z * v.z + v.w * v.w;
    }
    #pragma unroll
    for (int off = 32; off; off >>= 1) s += __shfl_down(s, off, 64);
    __shared__ float wsum[4];
    if ((threadIdx.x & 63) == 0) wsum[threadIdx.x >> 6] = s;
    __syncthreads();
    if (threadIdx.x == 0) norm2[d] = wsum[0] + wsum[1] + wsum[2] + wsum[3];
}

// ------- kernel 2: xs2 = bf16(x * rsqrt(norm2)) fragment-tiled ------------------
// xs2[((row>>4)*64 + k8)*128 + (row&15)*8 + e]  (row=0..511, col=k8*8+e)
__global__ __launch_bounds__(256) void cf_kxs2(const float* __restrict__ x,
                                               const float* __restrict__ norm2,
                                               __hip_bfloat16* __restrict__ xs2) {
    const int idx = blockIdx.x * 256 + threadIdx.x;
    const int row = idx >> 6;
    const int k8  = idx & 63;
    const float* xp = x + (size_t)row * DDIM + k8 * 8;
    f32x4 v0 = *(const f32x4*)(xp);
    f32x4 v1 = *(const f32x4*)(xp + 4);
    union { __hip_bfloat16 h[8]; bf16x8 v; } p;
    #pragma unroll
    for (int e = 0; e < 4; ++e) p.h[e]     = __float2bfloat16(v0[e] * rsqrtf(norm2[k8 * 8 + e]));
    #pragma unroll
    for (int e = 0; e < 4; ++e) p.h[4 + e] = __float2bfloat16(v1[e] * rsqrtf(norm2[k8 * 8 + 4 + e]));
    *(bf16x8*)(xs2 + ((size_t)((row >> 4) * 64 + k8) * 128 + (row & 15) * 8)) = p.v;
}

// ---------------- kernel 3: target logits, cos_m, final -------------------------
__global__ __launch_bounds__(64) void cf_ktgt(const float* __restrict__ x,
                                              const float* __restrict__ W,
                                              const float* __restrict__ norm2,
                                              const int* __restrict__ label,
                                              float* __restrict__ tl,
                                              float* __restrict__ cm,
                                              float* __restrict__ fl) {
    const int i = blockIdx.x;
    const int lane = threadIdx.x;
    const int lab = label[i];
    float s = 0.f;
    for (int d = lane; d < DDIM; d += 64)
        s += x[(size_t)i * DDIM + d] * rsqrtf(norm2[d]) * W[(size_t)d * C_DIM + lab];
    #pragma unroll
    for (int off = 32; off; off >>= 1) s += __shfl_down(s, off, 64);
    if (lane == 0) {
        float t = fminf(fmaxf(s, -1.f), 1.f);
        float sn = sqrtf(fmaxf(1.f - t * t, 0.f));
        float c = t * 0.8775825618903728f - sn * 0.479425538604203f; // cos(th+m)
        tl[i] = t;
        cm[i] = c;
        fl[i] = (t > -0.8775825618903728f) ? c : (t - 0.2397127693021015f);
    }
}

// ---------------- kernel 4: t = 0.01 * mean(target_logit) -----------------------
__global__ __launch_bounds__(512) void cf_kt(const float* __restrict__ tl,
                                             float* __restrict__ tout) {
    float s = tl[threadIdx.x];
    #pragma unroll
    for (int off = 32; off; off >>= 1) s += __shfl_down(s, off, 64);
    __shared__ float w[8];
    if ((threadIdx.x & 63) == 0) w[threadIdx.x >> 6] = s;
    __syncthreads();
    if (threadIdx.x == 0) {
        float tt = 0.f;
        #pragma unroll
        for (int j = 0; j < 8; ++j) tt += w[j];
        tout[0] = 0.01f * (tt / 512.0f);
    }
}

// ------------- shared epilogue (D[c][i] acc -> curricular logits, plain stores) -
__device__ __forceinline__ void cf_epilogue(f32acc (&acc)[4][4], int wv, int il,
                                            int hi, int cb,
                                            const int* __restrict__ label,
                                            const float* __restrict__ cosm,
                                            const float* __restrict__ finl,
                                            float t, float* __restrict__ out) {
    const int ib = wv * 64;
    #pragma unroll
    for (int n = 0; n < 4; ++n) {
        const int i = ib + n * 16 + il;
        const float cmv = cosm[i];
        const float flv = finl[i];
        const int lab = label[i];
        float* orow = out + (size_t)i * C_DIM;
        #pragma unroll
        for (int m = 0; m < 4; ++m) {
            const int c0 = cb + m * 16 + hi * 4;
            if (c0 < C_DIM) {
                f32x4 v = acc[m][n];
                f32x4 o;
                #pragma unroll
                for (int r = 0; r < 4; ++r) {
                    float cz = fminf(fmaxf(v[r], -1.f), 1.f);
                    float ov = (cz > cmv) ? cz * (t + cz) : cz;
                    if (c0 + r == lab) ov = flv;
                    o[r] = ov * 64.0f;
                }
                *(f32x4*)(orow + c0) = o;
            }
        }
    }
}

// ------------- GEMM core (LDS image already staged; round-4 proven) -------------
__device__ __forceinline__ void cf_gemm_core(const __hip_bfloat16* __restrict__ Bl,
                                             const __hip_bfloat16* __restrict__ xs2,
                                             int wv, int il, int hi,
                                             f32acc (&acc)[4][4]) {
    int crow[4];
    #pragma unroll
    for (int m = 0; m < 4; ++m) crow[m] = (m * 16 + il) * 512;

    auto loadB = [&](bf16x8 (&bb)[4], int kt) {
        #pragma unroll
        for (int n = 0; n < 4; ++n)
            bb[n] = *(const bf16x8*)(xs2 + (size_t)((wv * 4 + n) * 64 + kt * 4 + hi) * 128 + il * 8);
    };
    auto step = [&](const bf16x8 (&bb)[4], int kt) {
        bf16x8 a[4];
        #pragma unroll
        for (int m = 0; m < 4; ++m) {
            const int c = m * 16 + il;
            const int q = (kt * 4 + hi) ^ (c & 7);
            a[m] = *(const bf16x8*)&Bl[crow[m] + q * 8];
        }
        #pragma unroll
        for (int m = 0; m < 4; ++m)
            #pragma unroll
            for (int n = 0; n < 4; ++n)
                acc[m][n] = __builtin_amdgcn_mfma_f32_16x16x32_bf16(a[m], bb[n], acc[m][n], 0, 0, 0);
    };

    bf16x8 b0[4], b1[4];
    loadB(b0, 0);
    #pragma unroll
    for (int kt = 0; kt < 16; kt += 2) {
        if (kt + 1 < 16) loadB(b1, kt + 1);
        step(b0, kt);
        if (kt + 2 < 16) loadB(b0, kt + 2);
        if (kt + 1 < 16) step(b1, kt + 1);
    }
}

// ------------- kernel 5a: GEMM staging from bf16 Wb (fast path) -----------------
__global__ __launch_bounds__(512, 4) void cf_kgemm6(
    const __hip_bfloat16* __restrict__ xs2,
    const __hip_bfloat16* __restrict__ Wb,
    const int* __restrict__ label,
    const float* __restrict__ cosm,
    const float* __restrict__ finl,
    const float* __restrict__ tp,
    float* __restrict__ out) {
    __shared__ __attribute__((aligned(16))) __hip_bfloat16 Bl[64 * 512];

    const int tid  = threadIdx.x;
    const int wv   = tid >> 6;
    const int lane = tid & 63;
    const int il   = lane & 15;
    const int hi   = lane >> 4;
    const int cb   = blockIdx.x * BN;

    // stage: bf16 loads (half the bytes of round-4), register 8x4 transpose,
    // identical swizzled LDS image as round-4 (proven conflict profile).
    {
        const int c4 = (tid & 15) * 4;
        const int k8 = tid >> 4;        // 0..31
        const bool ok = (cb + c4) < C_DIM;
        #pragma unroll
        for (int kk2 = 0; kk2 < 2; ++kk2) {
            const int kb = kk2 * 256 + k8 * 8;
            u16x4 v[8];
            #pragma unroll
            for (int j = 0; j < 8; ++j) {
                if (ok) v[j] = *(const u16x4*)(Wb + (size_t)(kb + j) * C_DIM + cb + c4);
                else    v[j] = (u16x4){0, 0, 0, 0};
            }
            const int q = kk2 * 32 + k8;
            #pragma unroll
            for (int cc = 0; cc < 4; ++cc) {
                const int c = c4 + cc;
                union { unsigned short u[8]; bf16x8 b; } p;
                #pragma unroll
                for (int j = 0; j < 8; ++j) p.u[j] = v[j][cc];
                *(bf16x8*)&Bl[c * 512 + (q ^ (c & 7)) * 8] = p.b;
            }
        }
    }
    __syncthreads();

    f32acc acc[4][4];
    #pragma unroll
    for (int m = 0; m < 4; ++m)
        #pragma unroll
        for (int n = 0; n < 4; ++n)
            acc[m][n] = (f32acc){0.f, 0.f, 0.f, 0.f};

    cf_gemm_core(Bl, xs2, wv, il, hi, acc);
    cf_epilogue(acc, wv, il, hi, cb, label, cosm, finl, tp[0], out);
}

// ------------- kernel 5b: GEMM staging W f32 directly (fallback path) -----------
__global__ __launch_bounds__(512, 4) void cf_kgemm(
    const __hip_bfloat16* __restrict__ xs2,
    const float* __restrict__ W,
    const int* __restrict__ label,
    const float* __restrict__ cosm,
    const float* __restrict__ finl,
    const float* __restrict__ tp,
    float* __restrict__ out) {
    __shared__ __attribute__((aligned(16))) __hip_bfloat16 Bl[64 * 512];

    const int tid  = threadIdx.x;
    const int wv   = tid >> 6;
    const int lane = tid & 63;
    const int il   = lane & 15;
    const int hi   = lane >> 4;
    const int cb   = blockIdx.x * BN;

    {
        const int c4 = (tid & 15) * 4;
        const int k8 = tid >> 4;
        const bool ok = (cb + c4) < C_DIM;
        #pragma unroll
        for (int kk2 = 0; kk2 < 2; ++kk2) {
            const int kb = kk2 * 256 + k8 * 8;
            f32x4 v[8];
            #pragma unroll
            for (int j = 0; j < 8; ++j) {
                if (ok) v[j] = *(const f32x4*)(W + (size_t)(kb + j) * C_DIM + cb + c4);
                else    v[j] = (f32x4){0.f, 0.f, 0.f, 0.f};
            }
            const int q = kk2 * 32 + k8;
            #pragma unroll
            for (int cc = 0; cc < 4; ++cc) {
                const int c = c4 + cc;
                union { __hip_bfloat16 h[8]; bf16x8 b; } p;
                #pragma unroll
                for (int j = 0; j < 8; ++j) p.h[j] = __float2bfloat16(v[j][cc]);
                *(bf16x8*)&Bl[c * 512 + (q ^ (c & 7)) * 8] = p.b;
            }
        }
    }
    __syncthreads();

    f32acc acc[4][4];
    #pragma unroll
    for (int m = 0; m < 4; ++m)
        #pragma unroll
        for (int n = 0; n < 4; ++n)
            acc[m][n] = (f32acc){0.f, 0.f, 0.f, 0.f};

    cf_gemm_core(Bl, xs2, wv, il, hi, acc);
    cf_epilogue(acc, wv, il, hi, cb, label, cosm, finl, tp[0], out);
}

extern "C" void kernel_launch(void* const* d_in, const int* in_sizes, int n_in,
                              void* d_out, int out_size, void* d_ws, size_t ws_size,
                              hipStream_t stream) {
    const float* x   = (const float*)d_in[0];
    const float* W   = (const float*)d_in[1];
    const int* label = (const int*)d_in[2];
    float* out = (float*)d_out;

    char* ws = (char*)d_ws;
    float* norm2 = (float*)ws;             // 512 f32 (sum of squares)
    float* tl  = norm2 + 512;
    float* cm  = tl + 512;
    float* fl  = cm + 512;
    float* tsc = fl + 512;
    __hip_bfloat16* xs2 = (__hip_bfloat16*)(ws + 16384);       // 512 KB
    __hip_bfloat16* Wb  = (__hip_bfloat16*)(ws + (1 << 20));   // 102.4 MB

    const size_t need = (size_t)(1 << 20) + (size_t)DDIM * C_DIM * sizeof(__hip_bfloat16);
    const bool big = (ws_size >= need);

    if (big) cf_knorm2<<<DDIM, 256, 0, stream>>>(W, norm2, Wb);
    else     cf_knorm <<<DDIM, 256, 0, stream>>>(W, norm2);

    cf_kxs2<<<128, 256, 0, stream>>>(x, norm2, xs2);
    cf_ktgt<<<NROW, 64, 0, stream>>>(x, W, norm2, label, tl, cm, fl);
    cf_kt<<<1, 512, 0, stream>>>(tl, tsc);

    if (big)
        cf_kgemm6<<<NPANEL, 512, 0, stream>>>(xs2, Wb, label, cm, fl, tsc, out);
    else
        cf_kgemm <<<NPANEL, 512, 0, stream>>>(xs2, W, label, cm, fl, tsc, out);
}

// Round 10
// 203.865 us; speedup vs baseline: 1.0263x; 1.0263x over previous
//
#include <hip/hip_runtime.h>
#include <hip/hip_bf16.h>

#define C_DIM 100000
#define NROW 512
#define DDIM 512
#define BN 128
#define NPAN 782               // ceil(C_DIM/128); last panel: 32 valid cols
#define NXCD 8

typedef __attribute__((ext_vector_type(4))) float f32x4;
typedef __attribute__((ext_vector_type(8))) short bf16x8;
typedef __attribute__((ext_vector_type(4))) float f32acc;

// ---------------- kernel 1: norm2[d] = sum_c W[d][c]^2 --------------------------
__global__ __launch_bounds__(256) void cf_knorm(const float* __restrict__ W,
                                                float* __restrict__ norm2) {
    const int d = blockIdx.x;
    const float* row = W + (size_t)d * C_DIM;
    float s = 0.f;
    for (int c4 = threadIdx.x; c4 < C_DIM / 4; c4 += 256) {
        f32x4 v = *(const f32x4*)(row + c4 * 4);
        s += v.x * v.x + v.y * v.y + v.z * v.z + v.w * v.w;
    }
    #pragma unroll
    for (int off = 32; off; off >>= 1) s += __shfl_down(s, off, 64);
    __shared__ float wsum[4];
    if ((threadIdx.x & 63) == 0) wsum[threadIdx.x >> 6] = s;
    __syncthreads();
    if (threadIdx.x == 0) norm2[d] = wsum[0] + wsum[1] + wsum[2] + wsum[3];
}

// ------- kernel 2: xs2 = bf16(x * rsqrt(norm2)) fragment-tiled ------------------
// xs2[((row>>4)*64 + k8)*128 + (row&15)*8 + e]  (row=0..511, col=k8*8+e)
__global__ __launch_bounds__(256) void cf_kxs2(const float* __restrict__ x,
                                               const float* __restrict__ norm2,
                                               __hip_bfloat16* __restrict__ xs2) {
    const int idx = blockIdx.x * 256 + threadIdx.x;
    const int row = idx >> 6;
    const int k8  = idx & 63;
    const float* xp = x + (size_t)row * DDIM + k8 * 8;
    f32x4 v0 = *(const f32x4*)(xp);
    f32x4 v1 = *(const f32x4*)(xp + 4);
    union { __hip_bfloat16 h[8]; bf16x8 v; } p;
    #pragma unroll
    for (int e = 0; e < 4; ++e) p.h[e]     = __float2bfloat16(v0[e] * rsqrtf(norm2[k8 * 8 + e]));
    #pragma unroll
    for (int e = 0; e < 4; ++e) p.h[4 + e] = __float2bfloat16(v1[e] * rsqrtf(norm2[k8 * 8 + 4 + e]));
    *(bf16x8*)(xs2 + ((size_t)((row >> 4) * 64 + k8) * 128 + (row & 15) * 8)) = p.v;
}

// ---------------- kernel 3: target logits, cos_m, final -------------------------
__global__ __launch_bounds__(64) void cf_ktgt(const float* __restrict__ x,
                                              const float* __restrict__ W,
                                              const float* __restrict__ norm2,
                                              const int* __restrict__ label,
                                              float* __restrict__ tl,
                                              float* __restrict__ cm,
                                              float* __restrict__ fl) {
    const int i = blockIdx.x;
    const int lane = threadIdx.x;
    const int lab = label[i];
    float s = 0.f;
    for (int d = lane; d < DDIM; d += 64)
        s += x[(size_t)i * DDIM + d] * rsqrtf(norm2[d]) * W[(size_t)d * C_DIM + lab];
    #pragma unroll
    for (int off = 32; off; off >>= 1) s += __shfl_down(s, off, 64);
    if (lane == 0) {
        float t = fminf(fmaxf(s, -1.f), 1.f);
        float sn = sqrtf(fmaxf(1.f - t * t, 0.f));
        float c = t * 0.8775825618903728f - sn * 0.479425538604203f; // cos(th+m)
        tl[i] = t;
        cm[i] = c;
        fl[i] = (t > -0.8775825618903728f) ? c : (t - 0.2397127693021015f);
    }
}

// ---------------- kernel 4: t = 0.01 * mean(target_logit) -----------------------
__global__ __launch_bounds__(512) void cf_kt(const float* __restrict__ tl,
                                             float* __restrict__ tout) {
    float s = tl[threadIdx.x];
    #pragma unroll
    for (int off = 32; off; off >>= 1) s += __shfl_down(s, off, 64);
    __shared__ float w[8];
    if ((threadIdx.x & 63) == 0) w[threadIdx.x >> 6] = s;
    __syncthreads();
    if (threadIdx.x == 0) {
        float tt = 0.f;
        #pragma unroll
        for (int j = 0; j < 8; ++j) tt += w[j];
        tout[0] = 0.01f * (tt / 512.0f);
    }
}

// ---------------- kernel 5: BN=128 one-shot GEMM + fused epilogue ---------------
// 782 blocks (XCD-chunk-swizzled), 1024 thr / 16 waves. Full W panel (128 cols x
// 512 k) staged f32->bf16 into 128KB swizzled LDS once (one barrier). Wave =
// (wr=wv&7 -> rows wr*64) x (wc=wv>>3 -> cols wc*64); acc[4][4] as in round 4.
// Per output row each block now writes 512B contiguous (2x round-4's 256B) and
// same-XCD blocks cover adjacent panels -> DRAM-friendlier write stream.
__global__ __launch_bounds__(1024, 4) void cf_kgemm7(
    const __hip_bfloat16* __restrict__ xs2,
    const float* __restrict__ W,
    const int* __restrict__ label,
    const float* __restrict__ cosm,
    const float* __restrict__ finl,
    const float* __restrict__ tp,
    float* __restrict__ out) {
    __shared__ __attribute__((aligned(16))) __hip_bfloat16 Bl[BN * 512];  // 128KB

    const int tid  = threadIdx.x;
    const int wv   = tid >> 6;       // 0..15
    const int lane = tid & 63;
    const int il   = lane & 15;
    const int hi   = lane >> 4;
    const int wr   = wv & 7;         // row group: rows wr*64
    const int wc   = wv >> 3;        // col group: cols wc*64

    // bijective XCD-chunk swizzle (NPAN = 8*97 + 6)
    const int q = NPAN / NXCD, r = NPAN % NXCD;
    const int xcd = blockIdx.x % NXCD, pos = blockIdx.x / NXCD;
    const int pan = (xcd < r) ? xcd * (q + 1) + pos
                              : r * (q + 1) + (xcd - r) * q + pos;
    const int cb = pan * BN;

    // ---- stage full W panel: thread = col-quad (32) x k-octet (32), 2 halves ----
    {
        const int c4 = (tid & 31) * 4;   // 0..124
        const int k8 = tid >> 5;         // 0..31
        const bool ok = (cb + c4) < C_DIM;   // C_DIM%4==0 -> quad all-or-nothing
        #pragma unroll
        for (int kk2 = 0; kk2 < 2; ++kk2) {
            const int kb = kk2 * 256 + k8 * 8;
            f32x4 v[8];
            #pragma unroll
            for (int j = 0; j < 8; ++j) {
                if (ok) v[j] = *(const f32x4*)(W + (size_t)(kb + j) * C_DIM + cb + c4);
                else    v[j] = (f32x4){0.f, 0.f, 0.f, 0.f};
            }
            const int qq = kk2 * 32 + k8;
            #pragma unroll
            for (int cc = 0; cc < 4; ++cc) {
                const int c = c4 + cc;
                union { __hip_bfloat16 h[8]; bf16x8 b; } p;
                #pragma unroll
                for (int j = 0; j < 8; ++j) p.h[j] = __float2bfloat16(v[j][cc]);
                *(bf16x8*)&Bl[c * 512 + (qq ^ (c & 7)) * 8] = p.b;
            }
        }
    }
    __syncthreads();   // the only barrier

    f32acc acc[4][4];
    #pragma unroll
    for (int m = 0; m < 4; ++m)
        #pragma unroll
        for (int n = 0; n < 4; ++n)
            acc[m][n] = (f32acc){0.f, 0.f, 0.f, 0.f};

    int crow[4];
    #pragma unroll
    for (int m = 0; m < 4; ++m) crow[m] = (wc * 64 + m * 16 + il) * 512;

    #pragma unroll
    for (int kt = 0; kt < 16; ++kt) {
        bf16x8 bb[4];
        #pragma unroll
        for (int n = 0; n < 4; ++n)
            bb[n] = *(const bf16x8*)(xs2 + (size_t)((wr * 4 + n) * 64 + kt * 4 + hi) * 128 + il * 8);
        bf16x8 a[4];
        #pragma unroll
        for (int m = 0; m < 4; ++m) {
            const int c = wc * 64 + m * 16 + il;
            const int qq = (kt * 4 + hi) ^ (c & 7);
            a[m] = *(const bf16x8*)&Bl[crow[m] + qq * 8];
        }
        #pragma unroll
        for (int m = 0; m < 4; ++m)
            #pragma unroll
            for (int n = 0; n < 4; ++n)
                acc[m][n] = __builtin_amdgcn_mfma_f32_16x16x32_bf16(a[m], bb[n], acc[m][n], 0, 0, 0);
    }

    // fused epilogue (round-4 verified mapping): D[c][i]
    const float t = tp[0];
    const int ib = wr * 64;
    const int cbw = cb + wc * 64;
    #pragma unroll
    for (int n = 0; n < 4; ++n) {
        const int i = ib + n * 16 + il;
        const float cmv = cosm[i];
        const float flv = finl[i];
        const int lab = label[i];
        float* orow = out + (size_t)i * C_DIM;
        #pragma unroll
        for (int m = 0; m < 4; ++m) {
            const int c0 = cbw + m * 16 + hi * 4;
            if (c0 < C_DIM) {
                f32x4 v = acc[m][n];
                f32x4 o;
                #pragma unroll
                for (int rr = 0; rr < 4; ++rr) {
                    float cz = fminf(fmaxf(v[rr], -1.f), 1.f);
                    float ov = (cz > cmv) ? cz * (t + cz) : cz;
                    if (c0 + rr == lab) ov = flv;
                    o[rr] = ov * 64.0f;
                }
                *(f32x4*)(orow + c0) = o;
            }
        }
    }
}

extern "C" void kernel_launch(void* const* d_in, const int* in_sizes, int n_in,
                              void* d_out, int out_size, void* d_ws, size_t ws_size,
                              hipStream_t stream) {
    const float* x   = (const float*)d_in[0];
    const float* W   = (const float*)d_in[1];
    const int* label = (const int*)d_in[2];
    float* out = (float*)d_out;

    char* ws = (char*)d_ws;
    float* norm2 = (float*)ws;             // 512 f32 (sum of squares)
    float* tl  = norm2 + 512;
    float* cm  = tl + 512;
    float* fl  = cm + 512;
    float* tsc = fl + 512;
    __hip_bfloat16* xs2 = (__hip_bfloat16*)(ws + 16384);  // 512*512 bf16 = 512KB

    cf_knorm<<<DDIM, 256, 0, stream>>>(W, norm2);
    cf_kxs2<<<128, 256, 0, stream>>>(x, norm2, xs2);
    cf_ktgt<<<NROW, 64, 0, stream>>>(x, W, norm2, label, tl, cm, fl);
    cf_kt<<<1, 512, 0, stream>>>(tl, tsc);

    cf_kgemm7<<<NPAN, 1024, 0, stream>>>(xs2, W, label, cm, fl, tsc, out);
}